// Round 1
// 159.861 us; speedup vs baseline: 1.0182x; 1.0182x over previous
//
#include <hip/hip_runtime.h>
#include <hip/hip_bf16.h>

// Problem constants
#define BB   4
#define SS   2048
#define DM   256
#define HH   4
#define DHH  64
#define NCH  (SS / 64)   // 32 k-chunks of 64

typedef unsigned short ushort_t;
typedef unsigned int   uint_t;
using short8   = __attribute__((ext_vector_type(8))) short;
using ushort8  = __attribute__((ext_vector_type(8))) unsigned short;
using ushort4v = __attribute__((ext_vector_type(4))) unsigned short;
using float4v  = __attribute__((ext_vector_type(4))) float;

__device__ __forceinline__ ushort_t f2bf(float f) {
  uint_t u = __float_as_uint(f);
  uint_t r = (u + 0x7FFFu + ((u >> 16) & 1u)) >> 16;  // RNE
  return (ushort_t)r;
}

// ---------------------------------------------------------------------------
// Kernel 0: fused prep.
// Blocks 0..47: coalesced LDS-tiled transposes Wk/Wv/Wo -> bf16 WT[o][c].
// Blocks 48..303 (o = bi-48 = h*64+e):
//   M'col[d] = (d==e)/8 + (alpha/512)*sum_{a,r} W2[h,d,a,r]*W2[h,a,e,r]
//   WcT[o][c] = sum_d Wq[c][h*64+d] * M'col[d]   (rank-2 interaction folded
//   into the Q projection; scores collapse from 320 to 64 dims)
//   bc[o]     = sum_d bq[h*64+d]   * M'col[d]
// ---------------------------------------------------------------------------
__global__ __launch_bounds__(256) void k_pre(
    const float* __restrict__ Wk, const float* __restrict__ Wv,
    const float* __restrict__ Wo, const float* __restrict__ Wq,
    const float* __restrict__ bq, const float* __restrict__ W2,
    const float* __restrict__ alpha_p,
    ushort_t* __restrict__ WkT, ushort_t* __restrict__ WvT,
    ushort_t* __restrict__ WoT, ushort_t* __restrict__ WcT,
    float* __restrict__ bc) {
  __shared__ float sT[64 * 65];
  __shared__ __align__(16) float sM[64];
  const int t = threadIdx.x;
  const int bi = blockIdx.x;
  if (bi < 48) {
    int m = bi >> 4, tile = bi & 15;
    int ot = tile >> 2, ct = tile & 3;
    const float* src = (m == 0) ? Wk : (m == 1) ? Wv : Wo;
    ushort_t* dst = (m == 0) ? WkT : (m == 1) ? WvT : WoT;
#pragma unroll
    for (int it = 0; it < 16; ++it) {
      int i = it * 4 + (t >> 6), j = t & 63;
      sT[i * 65 + j] = src[(ct * 64 + i) * 256 + ot * 64 + j];
    }
    __syncthreads();
#pragma unroll
    for (int it = 0; it < 16; ++it) {
      int jj = it * 4 + (t >> 6), ii = t & 63;
      dst[(ot * 64 + jj) * 256 + ct * 64 + ii] = f2bf(sT[ii * 65 + jj]);
    }
  } else {
    int o = bi - 48;          // h*64 + e
    int h = o >> 6, e = o & 63;
    if (t < 64) {
      const float* Wd = W2 + h * 16384 + t * 256;
      const float* We = W2 + h * 16384 + e * 4;
      float s = 0.f;
#pragma unroll 8
      for (int a = 0; a < 64; ++a) {
        float4 x = *(const float4*)(Wd + a * 4);
        float4 y = *(const float4*)(We + a * 256);
        s += x.x * y.x + x.y * y.y + x.z * y.z + x.w * y.w;
      }
      sM[t] = (t == e ? 0.125f : 0.f) + alpha_p[0] * (1.f / 512.f) * s;
    }
    __syncthreads();
    const float* Wrow = Wq + t * 256 + h * 64;
    float s = 0.f;
#pragma unroll
    for (int d4 = 0; d4 < 16; ++d4) {
      float4 x = *(const float4*)(Wrow + d4 * 4);
      float4 mm = *(const float4*)(sM + d4 * 4);
      s += x.x * mm.x + x.y * mm.y + x.z * mm.z + x.w * mm.w;
    }
    WcT[o * 256 + t] = f2bf(s);
    if (t == 0) {
      float sb = 0.f;
      for (int d = 0; d < 64; ++d) sb += bq[h * 64 + d] * sM[d];
      bc[o] = sb;
    }
  }
}

// ---------------------------------------------------------------------------
// MFMA projection helper. MODE 0: row-major [bh][s][64] store (Q'/K).
// MODE 1: transposed [bh][d][s] store (V).
// ---------------------------------------------------------------------------
template <int MODE>
__device__ __forceinline__ void pgemm(
    const ushort_t* __restrict__ sX, const ushort_t* __restrict__ WT,
    const float* __restrict__ bias, int w, int g, int l16,
    int b, int s0, ushort_t* __restrict__ dst) {
  float4v acc[2];
  acc[0] = (float4v){0.f, 0.f, 0.f, 0.f};
  acc[1] = (float4v){0.f, 0.f, 0.f, 0.f};
#pragma unroll
  for (int kc = 0; kc < 8; ++kc) {
    short8 af = *(const short8*)&sX[l16 * 256 + (((kc * 4 + g) ^ (l16 & 7)) << 3)];
#pragma unroll
    for (int ct = 0; ct < 2; ++ct) {
      int col = w * 32 + ct * 16 + l16;
      short8 bf = *(const short8*)&WT[col * 256 + kc * 32 + g * 8];
      acc[ct] = __builtin_amdgcn_mfma_f32_16x16x32_bf16(af, bf, acc[ct], 0, 0, 0);
    }
  }
#pragma unroll
  for (int ct = 0; ct < 2; ++ct) {
    int col = w * 32 + ct * 16 + l16;
    float bv = bias[col];
    int h = col >> 6, d = col & 63;
    if (MODE == 1) {
      ushort4v pk;
#pragma unroll
      for (int r = 0; r < 4; ++r) pk[r] = f2bf(acc[ct][r] + bv);
      *(ushort4v*)&dst[((size_t)(b * HH + h) * DHH + d) * SS + s0 + g * 4] = pk;
    } else {
#pragma unroll
      for (int r = 0; r < 4; ++r)
        dst[((size_t)(b * HH + h) * SS + s0 + g * 4 + r) * DHH + d] =
            f2bf(acc[ct][r] + bv);
    }
  }
}

// ---------------------------------------------------------------------------
// Kernel 1: fused MFMA projections (Q'=X@Wc+bc, K, V). 512 blocks x 512 thr.
// ---------------------------------------------------------------------------
__global__ __launch_bounds__(512) void k_proj(
    const float* __restrict__ q_in, const float* __restrict__ k_in,
    const float* __restrict__ v_in,
    const float* __restrict__ bk, const float* __restrict__ bv,
    const ushort_t* __restrict__ WcT, const ushort_t* __restrict__ WkT,
    const ushort_t* __restrict__ WvT, const float* __restrict__ bc,
    ushort_t* __restrict__ Qa, ushort_t* __restrict__ Ka,
    ushort_t* __restrict__ VTg) {
  __shared__ ushort_t sXq[16 * 256];
  __shared__ ushort_t sXk[16 * 256];
  __shared__ ushort_t sXv[16 * 256];

  const int t = threadIdx.x;
  const int w = t >> 6, lane = t & 63, g = lane >> 4, l16 = lane & 15;
  const int row0 = blockIdx.x * 16;
  const int b = row0 >> 11, s0 = row0 & (SS - 1);

  {
    int r = t >> 5, cf = (t & 31) * 8;
    int sw = r * 256 + (((cf >> 3) ^ (r & 7)) << 3);
    const float* qp = q_in + (size_t)(row0 + r) * DM + cf;
    const float* kp = k_in + (size_t)(row0 + r) * DM + cf;
    const float* vp = v_in + (size_t)(row0 + r) * DM + cf;
    float4 a0 = *(const float4*)qp, a1 = *(const float4*)(qp + 4);
    float4 b0 = *(const float4*)kp, b1 = *(const float4*)(kp + 4);
    float4 c0 = *(const float4*)vp, c1 = *(const float4*)(vp + 4);
    ushort8 uq, uk, uv;
    uq[0] = f2bf(a0.x); uq[1] = f2bf(a0.y); uq[2] = f2bf(a0.z); uq[3] = f2bf(a0.w);
    uq[4] = f2bf(a1.x); uq[5] = f2bf(a1.y); uq[6] = f2bf(a1.z); uq[7] = f2bf(a1.w);
    uk[0] = f2bf(b0.x); uk[1] = f2bf(b0.y); uk[2] = f2bf(b0.z); uk[3] = f2bf(b0.w);
    uk[4] = f2bf(b1.x); uk[5] = f2bf(b1.y); uk[6] = f2bf(b1.z); uk[7] = f2bf(b1.w);
    uv[0] = f2bf(c0.x); uv[1] = f2bf(c0.y); uv[2] = f2bf(c0.z); uv[3] = f2bf(c0.w);
    uv[4] = f2bf(c1.x); uv[5] = f2bf(c1.y); uv[6] = f2bf(c1.z); uv[7] = f2bf(c1.w);
    *(ushort8*)&sXq[sw] = uq;
    *(ushort8*)&sXk[sw] = uk;
    *(ushort8*)&sXv[sw] = uv;
  }
  __syncthreads();

  pgemm<0>(sXq, WcT, bc, w, g, l16, b, s0, Qa);
  pgemm<0>(sXk, WkT, bk, w, g, l16, b, s0, Ka);
  pgemm<1>(sXv, WvT, bv, w, g, l16, b, s0, VTg);
}

// ---------------------------------------------------------------------------
// Kernel 2: flash attention, 64-dim scores, TQ=128, NO k-split.
// 256 blocks x 512 thr (8 waves). Each wave owns one 16-row q-strip.
// XCD-swizzled block id: blocks sharing a (b,h) land on the same XCD so K/V
// stay L2-resident (8 fetches -> 1). K/V LDS staging is double-buffered:
// one barrier per 64-k chunk, next chunk's global loads in flight under
// compute. Block sees the full k-range -> normalize in-kernel and write the
// attention output A directly as bf16 [b][s][h*64+d] (4 MB). Removes the
// 32 MB fp32 Opart + 2 MB lpart round-trip and k_out's combine pass.
// Fixed-offset softmax (exp(s-20) baked into MFMA acc init); P packed to
// bf16 by truncation (v_perm); l summed from truncated values. LDS 48 KB.
// ---------------------------------------------------------------------------
__global__ __launch_bounds__(512) void k_attn(
    const ushort_t* __restrict__ Qa, const ushort_t* __restrict__ Ka,
    const ushort_t* __restrict__ VTg, ushort_t* __restrict__ Abuf) {
  __shared__ ushort_t sK[2][64 * 64];   // 2 x 8 KB
  __shared__ ushort_t sV[2][64 * 64];   // 2 x 8 KB
  __shared__ ushort_t sPT[128 * 64];    // 16 KB

  const int t = threadIdx.x;
  const int w = t >> 6, lane = t & 63, g = lane >> 4, l16 = lane & 15;

  // XCD swizzle: consecutive block ids round-robin the 8 XCDs, so give each
  // residue class a fixed pair of bh values -> K/V working set 1 MB per XCD.
  const int id = blockIdx.x;
  const int qt = (id >> 3) & 15;
  const int bh = ((id & 7) << 1) | (id >> 7);
  const int q0 = qt * 128;

  // Q fragments for this wave's 16-row strip
  short8 qfrag[2];
  {
    const ushort_t* qp =
        Qa + ((size_t)bh * SS + q0 + w * 16 + l16) * DHH + g * 8;
    qfrag[0] = *(const short8*)(qp);
    qfrag[1] = *(const short8*)(qp + 32);
  }

  const ushort_t* KaB = Ka + (size_t)bh * SS * DHH;
  const ushort_t* VTB = VTg + (size_t)bh * DHH * SS;

  // staging: 512 threads, one short8 of K and one of V each per chunk
  const int r0 = t >> 3, c0 = t & 7;
  const int sw = r0 * 64 + ((c0 ^ (r0 & 7)) << 3);

  short8 kreg = *(const short8*)(KaB + (size_t)r0 * DHH + c0 * 8);
  short8 vreg = *(const short8*)(VTB + (size_t)r0 * SS + c0 * 8);
  *(short8*)(sK[0] + sw) = kreg;
  *(short8*)(sV[0] + sw) = vreg;
  kreg = *(const short8*)(KaB + (size_t)(64 + r0) * DHH + c0 * 8);
  vreg = *(const short8*)(VTB + (size_t)r0 * SS + 64 + c0 * 8);

  float l_run = 0.f;
  float4v oacc[4];
#pragma unroll
  for (int dj = 0; dj < 4; ++dj) oacc[dj] = (float4v){0.f, 0.f, 0.f, 0.f};
  const int qrow = w * 16 + l16;

  __syncthreads();

  for (int kch = 0; kch < NCH; ++kch) {
    const int cur = kch & 1;
    const ushort_t* sKc = sK[cur];
    const ushort_t* sVc = sV[cur];

    // ---- S^T, offset baked into acc init ----
    float4v sacc[4];
#pragma unroll
    for (int kj = 0; kj < 4; ++kj)
      sacc[kj] = (float4v){-20.f, -20.f, -20.f, -20.f};
#pragma unroll
    for (int kc = 0; kc < 2; ++kc) {
#pragma unroll
      for (int kj = 0; kj < 4; ++kj) {
        int krow = kj * 16 + l16;
        short8 kf = *(const short8*)(sKc + krow * 64 +
                                     (((kc * 4 + g) ^ (krow & 7)) << 3));
        sacc[kj] = __builtin_amdgcn_mfma_f32_16x16x32_bf16(
            kf, qfrag[kc], sacc[kj], 0, 0, 0);
      }
    }

    // ---- softmax: exp, truncate-pack, l from truncated values ----
    {
      float lp = 0.f;
#pragma unroll
      for (int kj = 0; kj < 4; ++kj) {
        float p0 = __expf(sacc[kj][0]);
        float p1 = __expf(sacc[kj][1]);
        float p2 = __expf(sacc[kj][2]);
        float p3 = __expf(sacc[kj][3]);
        uint_t u01 = __builtin_amdgcn_perm(__float_as_uint(p1),
                                           __float_as_uint(p0), 0x07060302u);
        uint_t u23 = __builtin_amdgcn_perm(__float_as_uint(p3),
                                           __float_as_uint(p2), 0x07060302u);
        lp += __uint_as_float(__float_as_uint(p0) & 0xFFFF0000u);
        lp += __uint_as_float(__float_as_uint(p1) & 0xFFFF0000u);
        lp += __uint_as_float(__float_as_uint(p2) & 0xFFFF0000u);
        lp += __uint_as_float(__float_as_uint(p3) & 0xFFFF0000u);
        int kbase = kj * 16 + g * 4;
        uint2 pack; pack.x = u01; pack.y = u23;
        *(uint2*)(sPT + qrow * 64 + (((kbase >> 3) ^ (qrow & 7)) << 3) +
                  (kbase & 7)) = pack;
      }
      l_run += lp;
    }

    // ---- PV: sPT rows wave-private, no barrier needed ----
#pragma unroll
    for (int ck = 0; ck < 2; ++ck) {
      short8 vb[4];
#pragma unroll
      for (int dj = 0; dj < 4; ++dj) {
        int vrow = dj * 16 + l16;
        vb[dj] = *(const short8*)(sVc + vrow * 64 +
                                  (((ck * 4 + g) ^ (vrow & 7)) << 3));
      }
      short8 pa = *(const short8*)(sPT + qrow * 64 +
                                   (((ck * 4 + g) ^ (qrow & 7)) << 3));
#pragma unroll
      for (int dj = 0; dj < 4; ++dj)
        oacc[dj] = __builtin_amdgcn_mfma_f32_16x16x32_bf16(
            pa, vb[dj], oacc[dj], 0, 0, 0);
    }

    // ---- double-buffer: write next chunk, issue loads for chunk+2 ----
    if (kch < NCH - 1) {
      *(short8*)(sK[cur ^ 1] + sw) = kreg;
      *(short8*)(sV[cur ^ 1] + sw) = vreg;
      if (kch < NCH - 2) {
        kreg = *(const short8*)(KaB + (size_t)((kch + 2) * 64 + r0) * DHH +
                                c0 * 8);
        vreg = *(const short8*)(VTB + (size_t)r0 * SS + (kch + 2) * 64 +
                                c0 * 8);
      }
    }
    __syncthreads();
  }

  // ---- epilogue: per-row 1/l, write bf16 A[b][s][h*64+d] ----
  l_run += __shfl_xor(l_run, 16, 64);
  l_run += __shfl_xor(l_run, 32, 64);  // all lanes: full sum for row l16
  float lrow[4];
#pragma unroll
  for (int r = 0; r < 4; ++r) lrow[r] = __shfl(l_run, g * 4 + r, 64);

  const int b = bh >> 2, h = bh & 3;
#pragma unroll
  for (int r = 0; r < 4; ++r) {
    float linv = 1.0f / lrow[r];
    size_t row = (size_t)b * SS + q0 + w * 16 + g * 4 + r;
#pragma unroll
    for (int dj = 0; dj < 4; ++dj)
      Abuf[row * DM + h * DHH + dj * 16 + l16] = f2bf(oacc[dj][r] * linv);
  }
}

// ---------------------------------------------------------------------------
// Kernel 3: Out = A @ Wo + bo. 512 blocks x 512 thr, 16 rows/block.
// A arrives already normalized bf16 -> stage + MFMA only.
// ---------------------------------------------------------------------------
__global__ __launch_bounds__(512) void k_out(
    const ushort_t* __restrict__ Abuf, const ushort_t* __restrict__ WoT,
    const float* __restrict__ bo, float* __restrict__ Out) {
  __shared__ ushort_t sA[16 * 256];
  const int t = threadIdx.x;
  const int w = t >> 6, lane = t & 63, g = lane >> 4, l16 = lane & 15;
  const int row0 = blockIdx.x * 16;
  {
    int r = t >> 5, cf = (t & 31) * 8;
    ushort8 u = *(const ushort8*)(Abuf + (size_t)(row0 + r) * DM + cf);
    *(ushort8*)&sA[r * 256 + (((cf >> 3) ^ (r & 7)) << 3)] = u;
  }
  __syncthreads();

  float4v acc[2];
  acc[0] = (float4v){0.f, 0.f, 0.f, 0.f};
  acc[1] = (float4v){0.f, 0.f, 0.f, 0.f};
#pragma unroll
  for (int kc = 0; kc < 8; ++kc) {
    short8 af = *(const short8*)&sA[l16 * 256 + (((kc * 4 + g) ^ (l16 & 7)) << 3)];
#pragma unroll
    for (int ct = 0; ct < 2; ++ct) {
      int col = w * 32 + ct * 16 + l16;
      short8 bf = *(const short8*)&WoT[col * 256 + kc * 32 + g * 8];
      acc[ct] = __builtin_amdgcn_mfma_f32_16x16x32_bf16(af, bf, acc[ct], 0, 0, 0);
    }
  }
#pragma unroll
  for (int ct = 0; ct < 2; ++ct) {
    int col = w * 32 + ct * 16 + l16;
    float bv = bo[col];
#pragma unroll
    for (int r = 0; r < 4; ++r)
      Out[(size_t)(row0 + g * 4 + r) * DM + col] = acc[ct][r] + bv;
  }
}

// ---------------------------------------------------------------------------
extern "C" void kernel_launch(void* const* d_in, const int* in_sizes, int n_in,
                              void* d_out, int out_size, void* d_ws, size_t ws_size,
                              hipStream_t stream) {
  (void)in_sizes; (void)n_in; (void)out_size; (void)ws_size;
  const float* q_in  = (const float*)d_in[0];
  const float* k_in  = (const float*)d_in[1];
  const float* v_in  = (const float*)d_in[2];
  const float* Wq    = (const float*)d_in[3];
  const float* bq    = (const float*)d_in[4];
  const float* Wk    = (const float*)d_in[5];
  const float* bk    = (const float*)d_in[6];
  const float* Wv    = (const float*)d_in[7];
  const float* bv    = (const float*)d_in[8];
  const float* W2    = (const float*)d_in[9];
  const float* alpha = (const float*)d_in[10];
  const float* Wo    = (const float*)d_in[11];
  const float* bo    = (const float*)d_in[12];
  float* out = (float*)d_out;

  // workspace layout (bytes):
  // Qa 4,194,304 | Ka 4,194,304 | VTg 4,194,304 | Abuf 4,194,304 |
  // WkT/WvT/WoT/WcT 4x131,072 | bc 1,024  => ~17.3 MB
  char* ws = (char*)d_ws;
  ushort_t* Qa   = (ushort_t*)ws;
  ushort_t* Ka   = (ushort_t*)(ws + 4194304);
  ushort_t* VTg  = (ushort_t*)(ws + 8388608);
  ushort_t* Abuf = (ushort_t*)(ws + 12582912);
  ushort_t* WkT  = (ushort_t*)(ws + 16777216);
  ushort_t* WvT  = (ushort_t*)(ws + 16908288);
  ushort_t* WoT  = (ushort_t*)(ws + 17039360);
  ushort_t* WcT  = (ushort_t*)(ws + 17170432);
  float*    bc   = (float*)(ws + 17301504);

  hipLaunchKernelGGL(k_pre, dim3(304), dim3(256), 0, stream,
                     Wk, Wv, Wo, Wq, bq, W2, alpha, WkT, WvT, WoT, WcT, bc);
  hipLaunchKernelGGL(k_proj, dim3(512), dim3(512), 0, stream,
                     q_in, k_in, v_in, bk, bv, WcT, WkT, WvT, bc, Qa, Ka, VTg);
  hipLaunchKernelGGL(k_attn, dim3(256), dim3(512), 0, stream,
                     Qa, Ka, VTg, Abuf);
  hipLaunchKernelGGL(k_out, dim3(512), dim3(512), 0, stream,
                     Abuf, WoT, bo, out);
}

// Round 2
// 159.458 us; speedup vs baseline: 1.0207x; 1.0025x over previous
//
#include <hip/hip_runtime.h>
#include <hip/hip_bf16.h>

// Problem constants
#define BB   4
#define SS   2048
#define DM   256
#define HH   4
#define DHH  64
#define NCHH 16   // k-chunks of 64 per half (2 halves in-block)

typedef unsigned short ushort_t;
typedef unsigned int   uint_t;
using short8   = __attribute__((ext_vector_type(8))) short;
using ushort8  = __attribute__((ext_vector_type(8))) unsigned short;
using ushort4v = __attribute__((ext_vector_type(4))) unsigned short;
using float4v  = __attribute__((ext_vector_type(4))) float;

__device__ __forceinline__ ushort_t f2bf(float f) {
  uint_t u = __float_as_uint(f);
  uint_t r = (u + 0x7FFFu + ((u >> 16) & 1u)) >> 16;  // RNE
  return (ushort_t)r;
}

// ---------------------------------------------------------------------------
// Kernel 0: fused prep.
// Blocks 0..47: coalesced LDS-tiled transposes Wk/Wv/Wo -> bf16 WT[o][c].
// Blocks 48..303 (o = bi-48 = h*64+e):
//   M'col[d] = (d==e)/8 + (alpha/512)*sum_{a,r} W2[h,d,a,r]*W2[h,a,e,r]
//   WcT[o][c] = sum_d Wq[c][h*64+d] * M'col[d]   (rank-2 interaction folded
//   into the Q projection; scores collapse from 320 to 64 dims)
//   bc[o]     = sum_d bq[h*64+d]   * M'col[d]
// ---------------------------------------------------------------------------
__global__ __launch_bounds__(256) void k_pre(
    const float* __restrict__ Wk, const float* __restrict__ Wv,
    const float* __restrict__ Wo, const float* __restrict__ Wq,
    const float* __restrict__ bq, const float* __restrict__ W2,
    const float* __restrict__ alpha_p,
    ushort_t* __restrict__ WkT, ushort_t* __restrict__ WvT,
    ushort_t* __restrict__ WoT, ushort_t* __restrict__ WcT,
    float* __restrict__ bc) {
  __shared__ float sT[64 * 65];
  __shared__ __align__(16) float sM[64];
  const int t = threadIdx.x;
  const int bi = blockIdx.x;
  if (bi < 48) {
    int m = bi >> 4, tile = bi & 15;
    int ot = tile >> 2, ct = tile & 3;
    const float* src = (m == 0) ? Wk : (m == 1) ? Wv : Wo;
    ushort_t* dst = (m == 0) ? WkT : (m == 1) ? WvT : WoT;
#pragma unroll
    for (int it = 0; it < 16; ++it) {
      int i = it * 4 + (t >> 6), j = t & 63;
      sT[i * 65 + j] = src[(ct * 64 + i) * 256 + ot * 64 + j];
    }
    __syncthreads();
#pragma unroll
    for (int it = 0; it < 16; ++it) {
      int jj = it * 4 + (t >> 6), ii = t & 63;
      dst[(ot * 64 + jj) * 256 + ct * 64 + ii] = f2bf(sT[ii * 65 + jj]);
    }
  } else {
    int o = bi - 48;          // h*64 + e
    int h = o >> 6, e = o & 63;
    if (t < 64) {
      const float* Wd = W2 + h * 16384 + t * 256;
      const float* We = W2 + h * 16384 + e * 4;
      float s = 0.f;
#pragma unroll 8
      for (int a = 0; a < 64; ++a) {
        float4 x = *(const float4*)(Wd + a * 4);
        float4 y = *(const float4*)(We + a * 256);
        s += x.x * y.x + x.y * y.y + x.z * y.z + x.w * y.w;
      }
      sM[t] = (t == e ? 0.125f : 0.f) + alpha_p[0] * (1.f / 512.f) * s;
    }
    __syncthreads();
    const float* Wrow = Wq + t * 256 + h * 64;
    float s = 0.f;
#pragma unroll
    for (int d4 = 0; d4 < 16; ++d4) {
      float4 x = *(const float4*)(Wrow + d4 * 4);
      float4 mm = *(const float4*)(sM + d4 * 4);
      s += x.x * mm.x + x.y * mm.y + x.z * mm.z + x.w * mm.w;
    }
    WcT[o * 256 + t] = f2bf(s);
    if (t == 0) {
      float sb = 0.f;
      for (int d = 0; d < 64; ++d) sb += bq[h * 64 + d] * sM[d];
      bc[o] = sb;
    }
  }
}

// ---------------------------------------------------------------------------
// MFMA projection helper. MODE 0: row-major [bh][s][64] store (Q'/K).
// MODE 1: transposed [bh][d][s] store (V).
// ---------------------------------------------------------------------------
template <int MODE>
__device__ __forceinline__ void pgemm(
    const ushort_t* __restrict__ sX, const ushort_t* __restrict__ WT,
    const float* __restrict__ bias, int w, int g, int l16,
    int b, int s0, ushort_t* __restrict__ dst) {
  float4v acc[2];
  acc[0] = (float4v){0.f, 0.f, 0.f, 0.f};
  acc[1] = (float4v){0.f, 0.f, 0.f, 0.f};
#pragma unroll
  for (int kc = 0; kc < 8; ++kc) {
    short8 af = *(const short8*)&sX[l16 * 256 + (((kc * 4 + g) ^ (l16 & 7)) << 3)];
#pragma unroll
    for (int ct = 0; ct < 2; ++ct) {
      int col = w * 32 + ct * 16 + l16;
      short8 bf = *(const short8*)&WT[col * 256 + kc * 32 + g * 8];
      acc[ct] = __builtin_amdgcn_mfma_f32_16x16x32_bf16(af, bf, acc[ct], 0, 0, 0);
    }
  }
#pragma unroll
  for (int ct = 0; ct < 2; ++ct) {
    int col = w * 32 + ct * 16 + l16;
    float bv = bias[col];
    int h = col >> 6, d = col & 63;
    if (MODE == 1) {
      ushort4v pk;
#pragma unroll
      for (int r = 0; r < 4; ++r) pk[r] = f2bf(acc[ct][r] + bv);
      *(ushort4v*)&dst[((size_t)(b * HH + h) * DHH + d) * SS + s0 + g * 4] = pk;
    } else {
#pragma unroll
      for (int r = 0; r < 4; ++r)
        dst[((size_t)(b * HH + h) * SS + s0 + g * 4 + r) * DHH + d] =
            f2bf(acc[ct][r] + bv);
    }
  }
}

// ---------------------------------------------------------------------------
// Kernel 1: fused MFMA projections (Q'=X@Wc+bc, K, V). 512 blocks x 512 thr.
// ---------------------------------------------------------------------------
__global__ __launch_bounds__(512) void k_proj(
    const float* __restrict__ q_in, const float* __restrict__ k_in,
    const float* __restrict__ v_in,
    const float* __restrict__ bk, const float* __restrict__ bv,
    const ushort_t* __restrict__ WcT, const ushort_t* __restrict__ WkT,
    const ushort_t* __restrict__ WvT, const float* __restrict__ bc,
    ushort_t* __restrict__ Qa, ushort_t* __restrict__ Ka,
    ushort_t* __restrict__ VTg) {
  __shared__ ushort_t sXq[16 * 256];
  __shared__ ushort_t sXk[16 * 256];
  __shared__ ushort_t sXv[16 * 256];

  const int t = threadIdx.x;
  const int w = t >> 6, lane = t & 63, g = lane >> 4, l16 = lane & 15;
  const int row0 = blockIdx.x * 16;
  const int b = row0 >> 11, s0 = row0 & (SS - 1);

  {
    int r = t >> 5, cf = (t & 31) * 8;
    int sw = r * 256 + (((cf >> 3) ^ (r & 7)) << 3);
    const float* qp = q_in + (size_t)(row0 + r) * DM + cf;
    const float* kp = k_in + (size_t)(row0 + r) * DM + cf;
    const float* vp = v_in + (size_t)(row0 + r) * DM + cf;
    float4 a0 = *(const float4*)qp, a1 = *(const float4*)(qp + 4);
    float4 b0 = *(const float4*)kp, b1 = *(const float4*)(kp + 4);
    float4 c0 = *(const float4*)vp, c1 = *(const float4*)(vp + 4);
    ushort8 uq, uk, uv;
    uq[0] = f2bf(a0.x); uq[1] = f2bf(a0.y); uq[2] = f2bf(a0.z); uq[3] = f2bf(a0.w);
    uq[4] = f2bf(a1.x); uq[5] = f2bf(a1.y); uq[6] = f2bf(a1.z); uq[7] = f2bf(a1.w);
    uk[0] = f2bf(b0.x); uk[1] = f2bf(b0.y); uk[2] = f2bf(b0.z); uk[3] = f2bf(b0.w);
    uk[4] = f2bf(b1.x); uk[5] = f2bf(b1.y); uk[6] = f2bf(b1.z); uk[7] = f2bf(b1.w);
    uv[0] = f2bf(c0.x); uv[1] = f2bf(c0.y); uv[2] = f2bf(c0.z); uv[3] = f2bf(c0.w);
    uv[4] = f2bf(c1.x); uv[5] = f2bf(c1.y); uv[6] = f2bf(c1.z); uv[7] = f2bf(c1.w);
    *(ushort8*)&sXq[sw] = uq;
    *(ushort8*)&sXk[sw] = uk;
    *(ushort8*)&sXv[sw] = uv;
  }
  __syncthreads();

  pgemm<0>(sXq, WcT, bc, w, g, l16, b, s0, Qa);
  pgemm<0>(sXk, WkT, bk, w, g, l16, b, s0, Ka);
  pgemm<1>(sXv, WvT, bv, w, g, l16, b, s0, VTg);
}

// ---------------------------------------------------------------------------
// Kernel 2: flash attention, 64-dim scores, TQ=128, in-block k-split x2.
// Grid 256 (16 qt x 16 bh, XCD-swizzled), block 512 = 8 waves.
// Waves 0-3 (half 0) process k in [0,1024); waves 4-7 (half 1) k in
// [1024,2048). Each wave owns TWO 16-row q-strips (s*64 + wl*16), so K/V/P
// fragments are reused across both strips: 20 ds_read_b128 per 32 MFMA
// (0.625 reads/MFMA vs 1.125 in the 1-strip version) -- attacks the
// LDS-read-bound regime. Each half has its own double-buffered K/V staging
// and its own P buffer; serial chunk chain is 16 (was 32). Halves merge
// O (fp32) and l through LDS in the epilogue -- no HBM partials.
// Fixed-offset softmax (exp(s-20) baked into MFMA acc init); P packed to
// bf16 by truncation (v_perm); l summed from truncated values.
// LDS 96 KB -> 1 block/CU (8 waves).
// ---------------------------------------------------------------------------
__global__ __launch_bounds__(512, 2) void k_attn(
    const ushort_t* __restrict__ Qa, const ushort_t* __restrict__ Ka,
    const ushort_t* __restrict__ VTg, ushort_t* __restrict__ Abuf) {
  __shared__ ushort_t sK[2 * 2 * 64 * 64];   // [half][buf][64*64]  32 KB
  __shared__ ushort_t sV[2 * 2 * 64 * 64];   // 32 KB
  __shared__ ushort_t sPT[2 * 128 * 64];     // [half][128*64]      32 KB

  const int t = threadIdx.x;
  const int w = t >> 6, lane = t & 63, g = lane >> 4, l16 = lane & 15;
  const int hv = w >> 2, wl = w & 3;

  // XCD swizzle: consecutive block ids round-robin the 8 XCDs; give each
  // residue class a fixed pair of bh values -> K/V L2-resident per XCD.
  const int id = blockIdx.x;
  const int qt = (id >> 3) & 15;
  const int bh = ((id & 7) << 1) | (id >> 7);
  const int q0 = qt * 128;

  // Q fragments: two 16-row strips per wave (rows s*64 + wl*16)
  short8 qfrag[2][2];
#pragma unroll
  for (int s = 0; s < 2; ++s) {
    const ushort_t* qp =
        Qa + ((size_t)bh * SS + q0 + s * 64 + wl * 16 + l16) * DHH + g * 8;
    qfrag[s][0] = *(const short8*)(qp);
    qfrag[s][1] = *(const short8*)(qp + 32);
  }

  const ushort_t* KaB = Ka + (size_t)bh * SS * DHH + (size_t)hv * 1024 * DHH;
  const ushort_t* VTB = VTg + (size_t)bh * DHH * SS + hv * 1024;

  // staging: 256 threads per half; each thread 2 short8 of K and 2 of V
  const int th = t & 255;
  const int r0 = th >> 2, c0 = th & 3;
  const int swA = r0 * 64 + (((c0 + 0) ^ (r0 & 7)) << 3);
  const int swB = r0 * 64 + (((c0 + 4) ^ (r0 & 7)) << 3);

  ushort_t* sKh = sK + hv * 8192;
  ushort_t* sVh = sV + hv * 8192;
  ushort_t* sPh = sPT + hv * 8192;

  short8 kreg[2], vreg[2];
  {
    // chunk 0 of this half -> LDS buf0
    kreg[0] = *(const short8*)(KaB + (size_t)r0 * DHH + (c0 + 0) * 8);
    kreg[1] = *(const short8*)(KaB + (size_t)r0 * DHH + (c0 + 4) * 8);
    vreg[0] = *(const short8*)(VTB + (size_t)r0 * SS + (c0 + 0) * 8);
    vreg[1] = *(const short8*)(VTB + (size_t)r0 * SS + (c0 + 4) * 8);
    *(short8*)(sKh + swA) = kreg[0];
    *(short8*)(sKh + swB) = kreg[1];
    *(short8*)(sVh + swA) = vreg[0];
    *(short8*)(sVh + swB) = vreg[1];
    // chunk 1 -> regs
    kreg[0] = *(const short8*)(KaB + (size_t)(64 + r0) * DHH + (c0 + 0) * 8);
    kreg[1] = *(const short8*)(KaB + (size_t)(64 + r0) * DHH + (c0 + 4) * 8);
    vreg[0] = *(const short8*)(VTB + (size_t)r0 * SS + 64 + (c0 + 0) * 8);
    vreg[1] = *(const short8*)(VTB + (size_t)r0 * SS + 64 + (c0 + 4) * 8);
  }

  float l_run[2] = {0.f, 0.f};
  float4v oacc[2][4];
#pragma unroll
  for (int s = 0; s < 2; ++s)
#pragma unroll
    for (int dj = 0; dj < 4; ++dj) oacc[s][dj] = (float4v){0.f, 0.f, 0.f, 0.f};

  __syncthreads();

  for (int kch = 0; kch < NCHH; ++kch) {
    const ushort_t* sKc = sKh + (kch & 1) * 4096;
    const ushort_t* sVc = sVh + (kch & 1) * 4096;

    // ---- S^T, offset baked into acc init; kf shared across both strips ----
    float4v sacc[2][4];
#pragma unroll
    for (int s = 0; s < 2; ++s)
#pragma unroll
      for (int kj = 0; kj < 4; ++kj)
        sacc[s][kj] = (float4v){-20.f, -20.f, -20.f, -20.f};
#pragma unroll
    for (int kc = 0; kc < 2; ++kc) {
#pragma unroll
      for (int kj = 0; kj < 4; ++kj) {
        int krow = kj * 16 + l16;
        short8 kf = *(const short8*)(sKc + krow * 64 +
                                     (((kc * 4 + g) ^ (krow & 7)) << 3));
        sacc[0][kj] = __builtin_amdgcn_mfma_f32_16x16x32_bf16(
            kf, qfrag[0][kc], sacc[0][kj], 0, 0, 0);
        sacc[1][kj] = __builtin_amdgcn_mfma_f32_16x16x32_bf16(
            kf, qfrag[1][kc], sacc[1][kj], 0, 0, 0);
      }
    }

    // ---- softmax: exp, truncate-pack, l from truncated values ----
#pragma unroll
    for (int s = 0; s < 2; ++s) {
      int qr = s * 64 + wl * 16 + l16;
      float lp = 0.f;
#pragma unroll
      for (int kj = 0; kj < 4; ++kj) {
        float p0 = __expf(sacc[s][kj][0]);
        float p1 = __expf(sacc[s][kj][1]);
        float p2 = __expf(sacc[s][kj][2]);
        float p3 = __expf(sacc[s][kj][3]);
        uint_t u01 = __builtin_amdgcn_perm(__float_as_uint(p1),
                                           __float_as_uint(p0), 0x07060302u);
        uint_t u23 = __builtin_amdgcn_perm(__float_as_uint(p3),
                                           __float_as_uint(p2), 0x07060302u);
        lp += __uint_as_float(__float_as_uint(p0) & 0xFFFF0000u);
        lp += __uint_as_float(__float_as_uint(p1) & 0xFFFF0000u);
        lp += __uint_as_float(__float_as_uint(p2) & 0xFFFF0000u);
        lp += __uint_as_float(__float_as_uint(p3) & 0xFFFF0000u);
        int kbase = kj * 16 + g * 4;
        uint2 pack; pack.x = u01; pack.y = u23;
        *(uint2*)(sPh + qr * 64 + (((kbase >> 3) ^ (qr & 7)) << 3) +
                  (kbase & 7)) = pack;
      }
      l_run[s] += lp;
    }

    // ---- PV: vb shared across strips; sPh rows wave-private, no barrier ----
#pragma unroll
    for (int ck = 0; ck < 2; ++ck) {
      short8 vb[4];
#pragma unroll
      for (int dj = 0; dj < 4; ++dj) {
        int vrow = dj * 16 + l16;
        vb[dj] = *(const short8*)(sVc + vrow * 64 +
                                  (((ck * 4 + g) ^ (vrow & 7)) << 3));
      }
#pragma unroll
      for (int s = 0; s < 2; ++s) {
        int qr = s * 64 + wl * 16 + l16;
        short8 pa = *(const short8*)(sPh + qr * 64 +
                                     (((ck * 4 + g) ^ (qr & 7)) << 3));
#pragma unroll
        for (int dj = 0; dj < 4; ++dj)
          oacc[s][dj] = __builtin_amdgcn_mfma_f32_16x16x32_bf16(
              pa, vb[dj], oacc[s][dj], 0, 0, 0);
      }
    }

    // ---- double-buffer: write next chunk, issue loads for chunk+2 ----
    if (kch < NCHH - 1) {
      ushort_t* sKn = sKh + ((kch & 1) ^ 1) * 4096;
      ushort_t* sVn = sVh + ((kch & 1) ^ 1) * 4096;
      *(short8*)(sKn + swA) = kreg[0];
      *(short8*)(sKn + swB) = kreg[1];
      *(short8*)(sVn + swA) = vreg[0];
      *(short8*)(sVn + swB) = vreg[1];
      if (kch < NCHH - 2) {
        size_t krow = (size_t)((kch + 2) * 64 + r0);
        kreg[0] = *(const short8*)(KaB + krow * DHH + (c0 + 0) * 8);
        kreg[1] = *(const short8*)(KaB + krow * DHH + (c0 + 4) * 8);
        vreg[0] = *(const short8*)(VTB + (size_t)r0 * SS + (kch + 2) * 64 +
                                   (c0 + 0) * 8);
        vreg[1] = *(const short8*)(VTB + (size_t)r0 * SS + (kch + 2) * 64 +
                                   (c0 + 4) * 8);
      }
    }
    __syncthreads();
  }

  // ---- epilogue: merge halves through LDS, normalize, write bf16 A ----
#pragma unroll
  for (int s = 0; s < 2; ++s) {
    l_run[s] += __shfl_xor(l_run[s], 16, 64);
    l_run[s] += __shfl_xor(l_run[s], 32, 64);  // all lanes: l for row l16
  }

  float* Of = (float*)sK;   // 128 rows x 64 cols fp32 = 32 KB
  float* sL = (float*)sV;   // 128 floats

  if (hv == 1) {
#pragma unroll
    for (int s = 0; s < 2; ++s) {
      if (g == 0) sL[s * 64 + wl * 16 + l16] = l_run[s];
#pragma unroll
      for (int r = 0; r < 4; ++r) {
        int row = s * 64 + wl * 16 + g * 4 + r;
#pragma unroll
        for (int dj = 0; dj < 4; ++dj)
          Of[row * 64 + dj * 16 + l16] = oacc[s][dj][r];
      }
    }
  }
  __syncthreads();

  if (hv == 0) {
    const int b = bh >> 2, h = bh & 3;
#pragma unroll
    for (int s = 0; s < 2; ++s) {
      float lt = l_run[s] + sL[s * 64 + wl * 16 + l16];
#pragma unroll
      for (int r = 0; r < 4; ++r) {
        float lr = __shfl(lt, g * 4 + r, 64);
        float linv = 1.0f / lr;
        int lrow = s * 64 + wl * 16 + g * 4 + r;
        size_t row = (size_t)b * SS + q0 + lrow;
#pragma unroll
        for (int dj = 0; dj < 4; ++dj) {
          float v = oacc[s][dj][r] + Of[lrow * 64 + dj * 16 + l16];
          Abuf[row * DM + h * DHH + dj * 16 + l16] = f2bf(v * linv);
        }
      }
    }
  }
}

// ---------------------------------------------------------------------------
// Kernel 3: Out = A @ Wo + bo. 512 blocks x 512 thr, 16 rows/block.
// A arrives already normalized bf16 -> stage + MFMA only.
// ---------------------------------------------------------------------------
__global__ __launch_bounds__(512) void k_out(
    const ushort_t* __restrict__ Abuf, const ushort_t* __restrict__ WoT,
    const float* __restrict__ bo, float* __restrict__ Out) {
  __shared__ ushort_t sA[16 * 256];
  const int t = threadIdx.x;
  const int w = t >> 6, lane = t & 63, g = lane >> 4, l16 = lane & 15;
  const int row0 = blockIdx.x * 16;
  {
    int r = t >> 5, cf = (t & 31) * 8;
    ushort8 u = *(const ushort8*)(Abuf + (size_t)(row0 + r) * DM + cf);
    *(ushort8*)&sA[r * 256 + (((cf >> 3) ^ (r & 7)) << 3)] = u;
  }
  __syncthreads();

  float4v acc[2];
  acc[0] = (float4v){0.f, 0.f, 0.f, 0.f};
  acc[1] = (float4v){0.f, 0.f, 0.f, 0.f};
#pragma unroll
  for (int kc = 0; kc < 8; ++kc) {
    short8 af = *(const short8*)&sA[l16 * 256 + (((kc * 4 + g) ^ (l16 & 7)) << 3)];
#pragma unroll
    for (int ct = 0; ct < 2; ++ct) {
      int col = w * 32 + ct * 16 + l16;
      short8 bf = *(const short8*)&WoT[col * 256 + kc * 32 + g * 8];
      acc[ct] = __builtin_amdgcn_mfma_f32_16x16x32_bf16(af, bf, acc[ct], 0, 0, 0);
    }
  }
#pragma unroll
  for (int ct = 0; ct < 2; ++ct) {
    int col = w * 32 + ct * 16 + l16;
    float bv = bo[col];
#pragma unroll
    for (int r = 0; r < 4; ++r)
      Out[(size_t)(row0 + g * 4 + r) * DM + col] = acc[ct][r] + bv;
  }
}

// ---------------------------------------------------------------------------
extern "C" void kernel_launch(void* const* d_in, const int* in_sizes, int n_in,
                              void* d_out, int out_size, void* d_ws, size_t ws_size,
                              hipStream_t stream) {
  (void)in_sizes; (void)n_in; (void)out_size; (void)ws_size;
  const float* q_in  = (const float*)d_in[0];
  const float* k_in  = (const float*)d_in[1];
  const float* v_in  = (const float*)d_in[2];
  const float* Wq    = (const float*)d_in[3];
  const float* bq    = (const float*)d_in[4];
  const float* Wk    = (const float*)d_in[5];
  const float* bk    = (const float*)d_in[6];
  const float* Wv    = (const float*)d_in[7];
  const float* bv    = (const float*)d_in[8];
  const float* W2    = (const float*)d_in[9];
  const float* alpha = (const float*)d_in[10];
  const float* Wo    = (const float*)d_in[11];
  const float* bo    = (const float*)d_in[12];
  float* out = (float*)d_out;

  // workspace layout (bytes):
  // Qa 4,194,304 | Ka 4,194,304 | VTg 4,194,304 | Abuf 4,194,304 |
  // WkT/WvT/WoT/WcT 4x131,072 | bc 1,024  => ~17.3 MB
  char* ws = (char*)d_ws;
  ushort_t* Qa   = (ushort_t*)ws;
  ushort_t* Ka   = (ushort_t*)(ws + 4194304);
  ushort_t* VTg  = (ushort_t*)(ws + 8388608);
  ushort_t* Abuf = (ushort_t*)(ws + 12582912);
  ushort_t* WkT  = (ushort_t*)(ws + 16777216);
  ushort_t* WvT  = (ushort_t*)(ws + 16908288);
  ushort_t* WoT  = (ushort_t*)(ws + 17039360);
  ushort_t* WcT  = (ushort_t*)(ws + 17170432);
  float*    bc   = (float*)(ws + 17301504);

  hipLaunchKernelGGL(k_pre, dim3(304), dim3(256), 0, stream,
                     Wk, Wv, Wo, Wq, bq, W2, alpha, WkT, WvT, WoT, WcT, bc);
  hipLaunchKernelGGL(k_proj, dim3(512), dim3(512), 0, stream,
                     q_in, k_in, v_in, bk, bv, WcT, WkT, WvT, bc, Qa, Ka, VTg);
  hipLaunchKernelGGL(k_attn, dim3(256), dim3(512), 0, stream,
                     Qa, Ka, VTg, Abuf);
  hipLaunchKernelGGL(k_out, dim3(512), dim3(512), 0, stream,
                     Abuf, WoT, bo, out);
}